// Round 2
// baseline (800.628 us; speedup 1.0000x reference)
//
#include <hip/hip_runtime.h>
#include <hip/hip_bf16.h>
#include <math.h>

// Problem dims (fixed by the reference)
#define DD 1024
#define HH 4096
#define TT 8192
#define KK1 (3*DD)    // 3072  (k=0 folded into bias)
#define KK2 (3*HH)    // 12288

typedef __attribute__((ext_vector_type(4))) float f32x4;
typedef __attribute__((ext_vector_type(8))) __bf16 bf16x8;
typedef __attribute__((ext_vector_type(8))) unsigned short u16x8;

__device__ __forceinline__ ushort f2bf(float f) {
    union { float f; unsigned u; } v; v.f = f;
    unsigned r = v.u + 0x7FFFu + ((v.u >> 16) & 1u);   // RNE
    return (ushort)(r >> 16);
}
__device__ __forceinline__ float bf2f(ushort u) {
    union { unsigned u; float f; } v; v.u = ((unsigned)u) << 16;
    return v.f;
}
__device__ __forceinline__ float clip1(float v){ return fminf(fmaxf(v, -1.f), 1.f); }
__device__ __forceinline__ float clip5(float v){ return fminf(fmaxf(v, -5.f), 5.f); }

__device__ __forceinline__ void gload_lds16(const void* g, void* l) {
    __builtin_amdgcn_global_load_lds((const __attribute__((address_space(1))) void*)g,
                                     (__attribute__((address_space(3))) void*)l, 16, 0, 0);
}

// ---- pack coeff [N,4,DIN] fp32 -> B^T bf16 [N][3*DIN] (clip to [-1,1]); k=0 slice -> bias[N]
template<int DIN>
__global__ __launch_bounds__(256) void pack_b(const float* __restrict__ c,
                                              ushort* __restrict__ Bp,
                                              float* __restrict__ bias) {
    const int n = blockIdx.x;
    const float* src = c + (size_t)n * 4 * DIN;
    ushort* dst = Bp + (size_t)n * 3 * DIN;
    float bsum = 0.f;
    for (int d = threadIdx.x; d < DIN; d += 256) {
        bsum += clip1(src[d]);
        dst[d]         = f2bf(clip1(src[DIN + d]));
        dst[DIN + d]   = f2bf(clip1(src[2*DIN + d]));
        dst[2*DIN + d] = f2bf(clip1(src[3*DIN + d]));
    }
    #pragma unroll
    for (int off = 32; off > 0; off >>= 1) bsum += __shfl_down(bsum, off, 64);
    __shared__ float red[4];
    const int wave = threadIdx.x >> 6, lane = threadIdx.x & 63;
    if (lane == 0) red[wave] = bsum;
    __syncthreads();
    if (threadIdx.x == 0) bias[n] = red[0] + red[1] + red[2] + red[3];
}

// ---- m97-style bf16 GEMM, 128x128 tile, BK=32, A built in-LDS from source.
// EPI=1: A from x fp32 (clip5, ^p);  C -> *0.1+bias, clip5, gelu, clip5 -> g bf16 [T][H]
// EPI=2: A from g bf16 (^p; p==0 via DMA); C -> *0.1+bias, clip5, +resid -> yout fp32 [T][D]
template<int EPI>
__global__ __launch_bounds__(256) void gemm_k(
    const void* __restrict__ Asrc, const ushort* __restrict__ Bt,
    const float* __restrict__ bias,
    ushort* __restrict__ gout,
    const float* __restrict__ resid, float* __restrict__ yout)
{
    constexpr int N  = (EPI == 1) ? HH : DD;
    constexpr int K  = (EPI == 1) ? KK1 : KK2;
    constexpr int SD = (EPI == 1) ? DD : HH;   // width of one power group

    __shared__ alignas(16) ushort As[128 * 32];
    __shared__ alignas(16) ushort Bs[128 * 32];
    const int tid  = threadIdx.x;
    const int lane = tid & 63;
    const int wave = tid >> 6;
    const int wrow = wave >> 1, wcol = wave & 1;      // 2x2 waves of 64x64
    const int m0 = blockIdx.y * 128, n0 = blockIdx.x * 128;
    const int ln15 = lane & 15, l4 = lane >> 4;

    f32x4 acc[4][4];
    #pragma unroll
    for (int m = 0; m < 4; ++m)
        #pragma unroll
        for (int n = 0; n < 4; ++n)
            acc[m][n] = (f32x4){0.f, 0.f, 0.f, 0.f};

    for (int k0 = 0; k0 < K; k0 += 32) {
        const int p  = k0 / SD;          // uniform power index for this K-step
        const int d0 = k0 - p * SD;

        // B tile: always async DMA (packed bf16, contiguous rows)
        #pragma unroll
        for (int it = 0; it < 2; ++it) {
            const int c = it * 256 + tid;
            const int row = c >> 2, kc = (c & 3) * 8;
            gload_lds16(Bt + (size_t)(n0 + row) * K + k0 + kc, (char*)Bs + (size_t)c * 16);
        }

        if (EPI == 2 && p == 0) {
            // power-1 slice of g: direct DMA
            const ushort* G = (const ushort*)Asrc;
            #pragma unroll
            for (int it = 0; it < 2; ++it) {
                const int c = it * 256 + tid;
                const int row = c >> 2, kc = (c & 3) * 8;
                gload_lds16(G + (size_t)(m0 + row) * HH + d0 + kc, (char*)As + (size_t)c * 16);
            }
        } else if (EPI == 1) {
            // reg-stage from x fp32: clip + ^(p+1) -> bf16
            const float* X = (const float*)Asrc;
            #pragma unroll
            for (int it = 0; it < 2; ++it) {
                const int c = it * 256 + tid;
                const int row = c >> 2, cj = (c & 3) * 8;
                const float* src = X + (size_t)(m0 + row) * DD + d0 + cj;
                const float4 va = *reinterpret_cast<const float4*>(src);
                const float4 vb = *reinterpret_cast<const float4*>(src + 4);
                const float w[8] = {va.x, va.y, va.z, va.w, vb.x, vb.y, vb.z, vb.w};
                u16x8 u;
                #pragma unroll
                for (int j = 0; j < 8; ++j) {
                    const float v = clip5(w[j]);
                    const float r = (p == 0) ? v : (p == 1 ? v * v : v * v * v);
                    u[j] = f2bf(r);
                }
                *reinterpret_cast<u16x8*>(&As[row * 32 + cj]) = u;
            }
        } else {
            // reg-stage from g bf16: ^(p+1) -> bf16
            const ushort* G = (const ushort*)Asrc;
            #pragma unroll
            for (int it = 0; it < 2; ++it) {
                const int c = it * 256 + tid;
                const int row = c >> 2, cj = (c & 3) * 8;
                const u16x8 gv = *reinterpret_cast<const u16x8*>(
                    G + (size_t)(m0 + row) * HH + d0 + cj);
                u16x8 u;
                #pragma unroll
                for (int j = 0; j < 8; ++j) {
                    const float v = bf2f(gv[j]);
                    const float r = (p == 1) ? v * v : v * v * v;
                    u[j] = f2bf(r);
                }
                *reinterpret_cast<u16x8*>(&As[row * 32 + cj]) = u;
            }
        }

        asm volatile("s_waitcnt vmcnt(0)" ::: "memory");
        __syncthreads();

        bf16x8 af[4], bfr[4];
        #pragma unroll
        for (int m = 0; m < 4; ++m)
            af[m] = *reinterpret_cast<const bf16x8*>(&As[(wrow*64 + m*16 + ln15) * 32 + l4 * 8]);
        #pragma unroll
        for (int n = 0; n < 4; ++n)
            bfr[n] = *reinterpret_cast<const bf16x8*>(&Bs[(wcol*64 + n*16 + ln15) * 32 + l4 * 8]);

        #pragma unroll
        for (int m = 0; m < 4; ++m)
            #pragma unroll
            for (int n = 0; n < 4; ++n)
                acc[m][n] = __builtin_amdgcn_mfma_f32_16x16x32_bf16(af[m], bfr[n], acc[m][n], 0, 0, 0);
        __syncthreads();
    }

    // epilogue — C/D map: col = lane&15, row = (lane>>4)*4 + reg  [m89-verified]
    float bn[4];
    #pragma unroll
    for (int n = 0; n < 4; ++n) bn[n] = bias[n0 + wcol*64 + n*16 + ln15];

    #pragma unroll
    for (int m = 0; m < 4; ++m) {
        #pragma unroll
        for (int j = 0; j < 4; ++j) {
            const int gm = m0 + wrow*64 + m*16 + l4*4 + j;
            #pragma unroll
            for (int n = 0; n < 4; ++n) {
                const int gn = n0 + wcol*64 + n*16 + ln15;
                float v = 0.1f * (acc[m][n][j] + bn[n]);
                v = clip5(v);
                if (EPI == 1) {
                    float g = 0.5f * v * (1.f + erff(v * 0.70710678118654752f));
                    g = clip5(g);
                    gout[(size_t)gm * HH + gn] = f2bf(g);
                } else {
                    yout[(size_t)gm * DD + gn] = v + resid[(size_t)gm * DD + gn];
                }
            }
        }
    }
}

// ---- row LayerNorm over D=1024, in-place, one block per row
__global__ __launch_bounds__(256) void ln_k(float* y,
                                            const float* __restrict__ gamma,
                                            const float* __restrict__ beta) {
    const int t = blockIdx.x, tid = threadIdx.x;
    const float4 v = reinterpret_cast<const float4*>(y + (size_t)t * DD)[tid];
    float s  = v.x + v.y + v.z + v.w;
    float s2 = v.x*v.x + v.y*v.y + v.z*v.z + v.w*v.w;
    #pragma unroll
    for (int off = 32; off > 0; off >>= 1) {
        s  += __shfl_down(s,  off, 64);
        s2 += __shfl_down(s2, off, 64);
    }
    __shared__ float rs[4], rs2[4];
    const int wave = tid >> 6, lane = tid & 63;
    if (lane == 0) { rs[wave] = s; rs2[wave] = s2; }
    __syncthreads();
    s  = rs[0] + rs[1] + rs[2] + rs[3];
    s2 = rs2[0] + rs2[1] + rs2[2] + rs2[3];
    const float mu  = s * (1.f / DD);
    const float var = s2 * (1.f / DD) - mu * mu;
    const float inv = rsqrtf(var + 1e-5f);
    const float4 g = reinterpret_cast<const float4*>(gamma)[tid];
    const float4 b = reinterpret_cast<const float4*>(beta)[tid];
    float4 o;
    o.x = (v.x - mu) * inv * g.x + b.x;
    o.y = (v.y - mu) * inv * g.y + b.y;
    o.z = (v.z - mu) * inv * g.z + b.z;
    o.w = (v.w - mu) * inv * g.w + b.w;
    reinterpret_cast<float4*>(y + (size_t)t * DD)[tid] = o;
}

extern "C" void kernel_launch(void* const* d_in, const int* in_sizes, int n_in,
                              void* d_out, int out_size, void* d_ws, size_t ws_size,
                              hipStream_t stream) {
    const float* x     = (const float*)d_in[0];
    const float* c1    = (const float*)d_in[1];
    const float* c2    = (const float*)d_in[2];
    const float* gamma = (const float*)d_in[3];
    const float* beta  = (const float*)d_in[4];
    float* out = (float*)d_out;

    // compact workspace: peak 92,295,168 B (~88 MiB)
    char* ws = (char*)d_ws;
    const size_t OFF_G     = 0;            // g bf16 [TT][HH] = 67,108,864
    const size_t OFF_B     = 67108864;     // B1p/B2p shared (sequential liveness) = 25,165,824
    const size_t OFF_BIAS1 = 92274688;     // HH*4
    const size_t OFF_BIAS2 = 92291072;     // DD*4

    ushort* gbuf  = (ushort*)(ws + OFF_G);
    ushort* B1p   = (ushort*)(ws + OFF_B);
    ushort* B2p   = (ushort*)(ws + OFF_B);
    float*  bias1 = (float*) (ws + OFF_BIAS1);
    float*  bias2 = (float*) (ws + OFF_BIAS2);

    pack_b<DD><<<HH, 256, 0, stream>>>(c1, B1p, bias1);
    gemm_k<1><<<dim3(HH / 128, TT / 128), 256, 0, stream>>>(
        (const void*)x, B1p, bias1, gbuf, nullptr, nullptr);
    pack_b<HH><<<DD, 256, 0, stream>>>(c2, B2p, bias2);      // reuses B region after GEMM1
    gemm_k<2><<<dim3(DD / 128, TT / 128), 256, 0, stream>>>(
        (const void*)gbuf, B2p, bias2, nullptr, x, (float*)out);
    ln_k<<<TT, 256, 0, stream>>>(out, gamma, beta);
}

// Round 3
// 645.276 us; speedup vs baseline: 1.2408x; 1.2408x over previous
//
#include <hip/hip_runtime.h>
#include <hip/hip_bf16.h>
#include <math.h>

// Problem dims (fixed by the reference)
#define DD 1024
#define HH 4096
#define TT 8192

typedef __attribute__((ext_vector_type(4))) float f32x4;
typedef __attribute__((ext_vector_type(8))) __bf16 bf16x8;

__device__ __forceinline__ ushort f2bf(float f) {
    union { float f; unsigned u; } v; v.f = f;
    unsigned r = v.u + 0x7FFFu + ((v.u >> 16) & 1u);   // RNE
    return (ushort)(r >> 16);
}
__device__ __forceinline__ float clip1(float v){ return fminf(fmaxf(v, -1.f), 1.f); }
__device__ __forceinline__ float clip5(float v){ return fminf(fmaxf(v, -5.f), 5.f); }

__device__ __forceinline__ void gload_lds16(const void* g, void* l) {
    __builtin_amdgcn_global_load_lds((const __attribute__((address_space(1))) void*)g,
                                     (__attribute__((address_space(3))) void*)l, 16, 0, 0);
}

// ---- pack coeff [N,4,DIN] fp32 -> B^T bf16 [N][3*DIN] (clip to [-1,1]); k=0 slice -> bias[N]
template<int DIN>
__global__ __launch_bounds__(256) void pack_b(const float* __restrict__ c,
                                              ushort* __restrict__ Bp,
                                              float* __restrict__ bias) {
    const int n = blockIdx.x;
    const float* src = c + (size_t)n * 4 * DIN;
    ushort* dst = Bp + (size_t)n * 3 * DIN;
    float bsum = 0.f;
    for (int d = threadIdx.x; d < DIN; d += 256) {
        bsum += clip1(src[d]);
        dst[d]         = f2bf(clip1(src[DIN + d]));
        dst[DIN + d]   = f2bf(clip1(src[2*DIN + d]));
        dst[2*DIN + d] = f2bf(clip1(src[3*DIN + d]));
    }
    #pragma unroll
    for (int off = 32; off > 0; off >>= 1) bsum += __shfl_down(bsum, off, 64);
    __shared__ float red[4];
    const int wave = threadIdx.x >> 6, lane = threadIdx.x & 63;
    if (lane == 0) red[wave] = bsum;
    __syncthreads();
    if (threadIdx.x == 0) bias[n] = red[0] + red[1] + red[2] + red[3];
}

// ---- 128x128 bf16 MFMA GEMM, K restructured as outer-d0 / inner-p.
// A-source tile read ONCE per d0; three power tiles built in LDS.
// EPI=1: A from x fp32 (clip5; v,v^2,v^3); C -> *0.1+bias, clip5, gelu, clip5 -> g bf16 [T][H]
// EPI=2: A from g bf16 (copy; g^2; g^3);  C -> *0.1+bias, clip5, +resid -> yout fp32 [T][D]
template<int EPI>
__global__ __launch_bounds__(256) void gemm_k(
    const void* __restrict__ Asrc, const __bf16* __restrict__ Bt,
    const float* __restrict__ bias,
    __bf16* __restrict__ gout,
    const float* __restrict__ resid, float* __restrict__ yout)
{
    constexpr int N  = (EPI == 1) ? HH : DD;
    constexpr int SD = (EPI == 1) ? DD : HH;   // source width (one power group)
    constexpr int K  = 3 * SD;

    __shared__ alignas(16) __bf16 As[3][128 * 32];
    __shared__ alignas(16) __bf16 Bs[128 * 32];
    const int tid  = threadIdx.x;
    const int lane = tid & 63;
    const int wave = tid >> 6;
    const int wrow = wave >> 1, wcol = wave & 1;      // 2x2 waves of 64x64
    const int m0 = blockIdx.y * 128, n0 = blockIdx.x * 128;
    const int ln15 = lane & 15, l4 = lane >> 4;

    f32x4 acc[4][4];
    #pragma unroll
    for (int m = 0; m < 4; ++m)
        #pragma unroll
        for (int n = 0; n < 4; ++n)
            acc[m][n] = (f32x4){0.f, 0.f, 0.f, 0.f};

    for (int d0 = 0; d0 < SD; d0 += 32) {
        // ---- A: read source tile once, build all three power tiles in LDS
        #pragma unroll
        for (int it = 0; it < 2; ++it) {
            const int c = it * 256 + tid;
            const int row = c >> 2, cj = (c & 3) * 8;
            bf16x8 u0, u1, u2;
            if (EPI == 1) {
                const float* src = (const float*)Asrc + (size_t)(m0 + row) * DD + d0 + cj;
                const float4 va = *reinterpret_cast<const float4*>(src);
                const float4 vb = *reinterpret_cast<const float4*>(src + 4);
                const float w[8] = {va.x, va.y, va.z, va.w, vb.x, vb.y, vb.z, vb.w};
                #pragma unroll
                for (int j = 0; j < 8; ++j) {
                    const float v  = clip5(w[j]);
                    const float v2 = v * v;
                    u0[j] = (__bf16)v;
                    u1[j] = (__bf16)v2;
                    u2[j] = (__bf16)(v2 * v);
                }
            } else {
                const __bf16* src = (const __bf16*)Asrc + (size_t)(m0 + row) * HH + d0 + cj;
                u0 = *reinterpret_cast<const bf16x8*>(src);   // g: raw copy, no VALU
                #pragma unroll
                for (int j = 0; j < 8; ++j) {
                    const float v  = (float)u0[j];
                    const float v2 = v * v;
                    u1[j] = (__bf16)v2;
                    u2[j] = (__bf16)(v2 * v);
                }
            }
            *reinterpret_cast<bf16x8*>(&As[0][row * 32 + cj]) = u0;
            *reinterpret_cast<bf16x8*>(&As[1][row * 32 + cj]) = u1;
            *reinterpret_cast<bf16x8*>(&As[2][row * 32 + cj]) = u2;
        }

        // ---- 3 MFMA phases, one per power; B tile DMA'd per phase
        #pragma unroll
        for (int p = 0; p < 3; ++p) {
            #pragma unroll
            for (int it = 0; it < 2; ++it) {
                const int c = it * 256 + tid;
                const int row = c >> 2, kc = (c & 3) * 8;
                gload_lds16(Bt + (size_t)(n0 + row) * K + p * SD + d0 + kc,
                            (char*)Bs + (size_t)c * 16);
            }
            asm volatile("s_waitcnt vmcnt(0)" ::: "memory");
            __syncthreads();

            bf16x8 af[4], bfr[4];
            #pragma unroll
            for (int m = 0; m < 4; ++m)
                af[m] = *reinterpret_cast<const bf16x8*>(&As[p][(wrow*64 + m*16 + ln15) * 32 + l4 * 8]);
            #pragma unroll
            for (int n = 0; n < 4; ++n)
                bfr[n] = *reinterpret_cast<const bf16x8*>(&Bs[(wcol*64 + n*16 + ln15) * 32 + l4 * 8]);

            #pragma unroll
            for (int m = 0; m < 4; ++m)
                #pragma unroll
                for (int n = 0; n < 4; ++n)
                    acc[m][n] = __builtin_amdgcn_mfma_f32_16x16x32_bf16(af[m], bfr[n], acc[m][n], 0, 0, 0);
            __syncthreads();
        }
    }

    // epilogue — C/D map: col = lane&15, row = (lane>>4)*4 + reg  [m89-verified]
    float bn[4];
    #pragma unroll
    for (int n = 0; n < 4; ++n) bn[n] = bias[n0 + wcol*64 + n*16 + ln15];

    #pragma unroll
    for (int m = 0; m < 4; ++m) {
        #pragma unroll
        for (int j = 0; j < 4; ++j) {
            const int gm = m0 + wrow*64 + m*16 + l4*4 + j;
            #pragma unroll
            for (int n = 0; n < 4; ++n) {
                const int gn = n0 + wcol*64 + n*16 + ln15;
                float v = 0.1f * (acc[m][n][j] + bn[n]);
                v = clip5(v);
                if (EPI == 1) {
                    float g = 0.5f * v * (1.f + erff(v * 0.70710678118654752f));
                    g = clip5(g);
                    gout[(size_t)gm * HH + gn] = (__bf16)g;
                } else {
                    yout[(size_t)gm * DD + gn] = v + resid[(size_t)gm * DD + gn];
                }
            }
        }
    }
}

// ---- row LayerNorm over D=1024, in-place, one block per row
__global__ __launch_bounds__(256) void ln_k(float* y,
                                            const float* __restrict__ gamma,
                                            const float* __restrict__ beta) {
    const int t = blockIdx.x, tid = threadIdx.x;
    const float4 v = reinterpret_cast<const float4*>(y + (size_t)t * DD)[tid];
    float s  = v.x + v.y + v.z + v.w;
    float s2 = v.x*v.x + v.y*v.y + v.z*v.z + v.w*v.w;
    #pragma unroll
    for (int off = 32; off > 0; off >>= 1) {
        s  += __shfl_down(s,  off, 64);
        s2 += __shfl_down(s2, off, 64);
    }
    __shared__ float rs[4], rs2[4];
    const int wave = tid >> 6, lane = tid & 63;
    if (lane == 0) { rs[wave] = s; rs2[wave] = s2; }
    __syncthreads();
    s  = rs[0] + rs[1] + rs[2] + rs[3];
    s2 = rs2[0] + rs2[1] + rs2[2] + rs2[3];
    const float mu  = s * (1.f / DD);
    const float var = s2 * (1.f / DD) - mu * mu;
    const float inv = rsqrtf(var + 1e-5f);
    const float4 g = reinterpret_cast<const float4*>(gamma)[tid];
    const float4 b = reinterpret_cast<const float4*>(beta)[tid];
    float4 o;
    o.x = (v.x - mu) * inv * g.x + b.x;
    o.y = (v.y - mu) * inv * g.y + b.y;
    o.z = (v.z - mu) * inv * g.z + b.z;
    o.w = (v.w - mu) * inv * g.w + b.w;
    reinterpret_cast<float4*>(y + (size_t)t * DD)[tid] = o;
}

extern "C" void kernel_launch(void* const* d_in, const int* in_sizes, int n_in,
                              void* d_out, int out_size, void* d_ws, size_t ws_size,
                              hipStream_t stream) {
    const float* x     = (const float*)d_in[0];
    const float* c1    = (const float*)d_in[1];
    const float* c2    = (const float*)d_in[2];
    const float* gamma = (const float*)d_in[3];
    const float* beta  = (const float*)d_in[4];
    float* out = (float*)d_out;

    // compact workspace: peak 92,295,168 B (~88 MiB)
    char* ws = (char*)d_ws;
    const size_t OFF_G     = 0;            // g bf16 [TT][HH] = 67,108,864
    const size_t OFF_B     = 67108864;     // B1p/B2p shared (sequential liveness) = 25,165,824
    const size_t OFF_BIAS1 = 92274688;     // HH*4
    const size_t OFF_BIAS2 = 92291072;     // DD*4

    __bf16* gbuf  = (__bf16*)(ws + OFF_G);
    ushort* B1p   = (ushort*)(ws + OFF_B);
    ushort* B2p   = (ushort*)(ws + OFF_B);
    float*  bias1 = (float*) (ws + OFF_BIAS1);
    float*  bias2 = (float*) (ws + OFF_BIAS2);

    pack_b<DD><<<HH, 256, 0, stream>>>(c1, B1p, bias1);
    gemm_k<1><<<dim3(HH / 128, TT / 128), 256, 0, stream>>>(
        (const void*)x, (const __bf16*)B1p, bias1, gbuf, nullptr, nullptr);
    pack_b<HH><<<DD, 256, 0, stream>>>(c2, B2p, bias2);      // reuses B region after GEMM1
    gemm_k<2><<<dim3(DD / 128, TT / 128), 256, 0, stream>>>(
        (const void*)gbuf, (const __bf16*)B2p, bias2, nullptr, x, (float*)out);
    ln_k<<<TT, 256, 0, stream>>>(out, gamma, beta);
}

// Round 4
// 541.968 us; speedup vs baseline: 1.4773x; 1.1906x over previous
//
#include <hip/hip_runtime.h>
#include <hip/hip_bf16.h>
#include <math.h>

// Problem dims (fixed by the reference)
#define DD 1024
#define HH 4096
#define TT 8192

typedef __attribute__((ext_vector_type(4))) float f32x4;
typedef __attribute__((ext_vector_type(8))) __bf16 bf16x8;
typedef __attribute__((ext_vector_type(4))) __bf16 bf16x4;

__device__ __forceinline__ ushort f2bf(float f) {
    union { float f; unsigned u; } v; v.f = f;
    unsigned r = v.u + 0x7FFFu + ((v.u >> 16) & 1u);   // RNE
    return (ushort)(r >> 16);
}
__device__ __forceinline__ float clip1(float v){ return fminf(fmaxf(v, -1.f), 1.f); }
__device__ __forceinline__ float clip5(float v){ return fminf(fmaxf(v, -5.f), 5.f); }

__device__ __forceinline__ void gload_lds16(const void* g, void* l) {
    __builtin_amdgcn_global_load_lds((const __attribute__((address_space(1))) void*)g,
                                     (__attribute__((address_space(3))) void*)l, 16, 0, 0);
}

template<int N> __device__ __forceinline__ void vmwait() {
    if      constexpr (N == 0) asm volatile("s_waitcnt vmcnt(0)" ::: "memory");
    else if constexpr (N == 2) asm volatile("s_waitcnt vmcnt(2)" ::: "memory");
    else if constexpr (N == 4) asm volatile("s_waitcnt vmcnt(4)" ::: "memory");
    else if constexpr (N == 6) asm volatile("s_waitcnt vmcnt(6)" ::: "memory");
    else if constexpr (N == 8) asm volatile("s_waitcnt vmcnt(8)" ::: "memory");
}

// ---- pack coeff [N,4,DIN] fp32 -> B^T bf16 [N][3*DIN] (clip); k=0 slice -> bias[N]
template<int DIN>
__global__ __launch_bounds__(256) void pack_b(const float* __restrict__ c,
                                              ushort* __restrict__ Bp,
                                              float* __restrict__ bias) {
    const int n = blockIdx.x;
    const float* src = c + (size_t)n * 4 * DIN;
    ushort* dst = Bp + (size_t)n * 3 * DIN;
    float bsum = 0.f;
    for (int d = threadIdx.x; d < DIN; d += 256) {
        bsum += clip1(src[d]);
        dst[d]         = f2bf(clip1(src[DIN + d]));
        dst[DIN + d]   = f2bf(clip1(src[2*DIN + d]));
        dst[2*DIN + d] = f2bf(clip1(src[3*DIN + d]));
    }
    #pragma unroll
    for (int off = 32; off > 0; off >>= 1) bsum += __shfl_down(bsum, off, 64);
    __shared__ float red[4];
    const int wave = threadIdx.x >> 6, lane = threadIdx.x & 63;
    if (lane == 0) red[wave] = bsum;
    __syncthreads();
    if (threadIdx.x == 0) bias[n] = red[0] + red[1] + red[2] + red[3];
}

// ---- 128x128 bf16 MFMA GEMM, counted-vmcnt pipeline.
// B: 4-slot LDS ring, tile DMA'd 3 phases ahead, pre-swizzled global source.
// A: x/g tile prefetched to regs (issue-early), powers ds_written (write-late),
//    3 power planes in LDS, XOR-swizzled.
// EPI=1: src x fp32; C -> *0.1+bias, clip5, gelu, clip5 -> g bf16 [T][H]
// EPI=2: src g bf16; C -> *0.1+bias, clip5, +resid -> y fp32 [T][D]
template<int EPI>
__global__ __launch_bounds__(256) void gemm_k(
    const void* __restrict__ Asrc, const __bf16* __restrict__ Bt,
    const float* __restrict__ bias,
    __bf16* __restrict__ gout,
    const float* __restrict__ resid, float* __restrict__ yout)
{
    constexpr int SD  = (EPI == 1) ? DD : HH;   // source width (one power group)
    constexpr int K   = 3 * SD;
    constexpr int NIT = SD / 32;
    constexpr int P12 = (EPI == 1) ? 8 : 6;     // steady-state vmcnt at phases 1,2

    __shared__ char LB[57344];                  // Bs ring 4*8192 @0; As 3*8192 @32768
    char* BsB = LB;
    char* AsB = LB + 32768;

    const int tid  = threadIdx.x;
    const int lane = tid & 63;
    const int wave = tid >> 6;
    const int wrow = wave >> 1, wcol = wave & 1;
    const int m0 = blockIdx.y * 128, n0 = blockIdx.x * 128;
    const int ln15 = lane & 15, l4 = lane >> 4;

    // swizzled frag-read byte offsets (T2: byte ^= ((row>>1)&3)<<4)
    int aoff[4], boff[4];
    #pragma unroll
    for (int m = 0; m < 4; ++m) {
        const int r = wrow*64 + m*16 + ln15;
        aoff[m] = r*64 + ((l4 ^ ((r>>1)&3)) << 4);
    }
    #pragma unroll
    for (int n = 0; n < 4; ++n) {
        const int r = wcol*64 + n*16 + ln15;
        boff[n] = r*64 + ((l4 ^ ((r>>1)&3)) << 4);
    }

    f32x4 acc[4][4];
    #pragma unroll
    for (int m = 0; m < 4; ++m)
        #pragma unroll
        for (int n = 0; n < 4; ++n)
            acc[m][n] = (f32x4){0.f, 0.f, 0.f, 0.f};

    // B tile DMA: kcol = p*SD + d0; LDS dest linear, global source pre-swizzled
    auto issueB = [&](int kcol, int slot) {
        char* dst = BsB + (size_t)slot * 8192;
        #pragma unroll
        for (int it = 0; it < 2; ++it) {
            const int c = it*256 + tid, row = c >> 2, ch = c & 3, fr = (row>>1)&3;
            gload_lds16(Bt + (size_t)(n0 + row) * K + kcol + ((ch ^ fr) * 8),
                        dst + (size_t)c * 16);
        }
    };

    // A-source prefetch registers
    f32x4  xw[4];   // EPI==1: 4 chunks of 4 floats
    bf16x8 gw[2];   // EPI==2: 2 chunks of 8 bf16

    auto issueX = [&](int i) {
        if constexpr (EPI == 1) {
            const float* X = (const float*)Asrc;
            #pragma unroll
            for (int k = 0; k < 4; ++k) {
                const int c = k*256 + tid, row = c >> 3, ch = c & 7;
                xw[k] = *reinterpret_cast<const f32x4*>(
                    X + (size_t)(m0 + row) * DD + 32*i + ch*4);
            }
        } else {
            const __bf16* G = (const __bf16*)Asrc;
            #pragma unroll
            for (int k = 0; k < 2; ++k) {
                const int c = k*256 + tid, row = c >> 2, ch = c & 3;
                gw[k] = *reinterpret_cast<const bf16x8*>(
                    G + (size_t)(m0 + row) * HH + 32*i + ch*8);
            }
        }
    };

    auto powers = [&]() {
        if constexpr (EPI == 1) {
            #pragma unroll
            for (int k = 0; k < 4; ++k) {
                const int c = k*256 + tid, row = c >> 3, ch = c & 7, fr = (row>>1)&3;
                bf16x4 u0, u1, u2;
                #pragma unroll
                for (int j = 0; j < 4; ++j) {
                    const float v  = clip5(xw[k][j]);
                    const float v2 = v * v;
                    u0[j] = (__bf16)v; u1[j] = (__bf16)v2; u2[j] = (__bf16)(v2 * v);
                }
                const int base = row*64 + ((ch*8) ^ (fr << 4));
                *reinterpret_cast<bf16x4*>(AsB +         base) = u0;
                *reinterpret_cast<bf16x4*>(AsB +  8192 + base) = u1;
                *reinterpret_cast<bf16x4*>(AsB + 16384 + base) = u2;
            }
        } else {
            #pragma unroll
            for (int k = 0; k < 2; ++k) {
                const int c = k*256 + tid, row = c >> 2, ch = c & 3, fr = (row>>1)&3;
                bf16x8 u1, u2;
                #pragma unroll
                for (int j = 0; j < 8; ++j) {
                    const float v  = (float)gw[k][j];
                    const float v2 = v * v;
                    u1[j] = (__bf16)v2; u2[j] = (__bf16)(v2 * v);
                }
                const int base = row*64 + (((ch << 4)) ^ (fr << 4));
                *reinterpret_cast<bf16x8*>(AsB +         base) = gw[k];
                *reinterpret_cast<bf16x8*>(AsB +  8192 + base) = u1;
                *reinterpret_cast<bf16x8*>(AsB + 16384 + base) = u2;
            }
        }
    };

    auto mfma_phase = [&](int p, int slot) {
        const char* As_ = AsB + p * 8192;
        const char* Bs_ = BsB + (size_t)slot * 8192;
        bf16x8 af[4], bf[4];
        #pragma unroll
        for (int m = 0; m < 4; ++m) af[m] = *reinterpret_cast<const bf16x8*>(As_ + aoff[m]);
        #pragma unroll
        for (int n = 0; n < 4; ++n) bf[n] = *reinterpret_cast<const bf16x8*>(Bs_ + boff[n]);
        __builtin_amdgcn_s_setprio(1);
        #pragma unroll
        for (int m = 0; m < 4; ++m)
            #pragma unroll
            for (int n = 0; n < 4; ++n)
                acc[m][n] = __builtin_amdgcn_mfma_f32_16x16x32_bf16(af[m], bf[n], acc[m][n], 0, 0, 0);
        __builtin_amdgcn_s_setprio(0);
    };

    // ---- prologue: x_0 regs, B tiles 0..2; powers(x_0) -> As
    issueX(0);
    issueB(0, 0);
    issueB(SD, 1);
    issueB(2*SD, 2);
    powers();                                   // compiler auto-waits xw (vmcnt(6))
    asm volatile("s_waitcnt lgkmcnt(0)" ::: "memory");

    for (int i = 0; i < NIT; ++i) {
        const bool nl = (i + 1 < NIT);
        const int s = 3*i;
        const int d1 = 32*(i+1);
        // ---- phase 0 (power 1, tile s)
        vmwait<4>();
        __builtin_amdgcn_s_barrier();
        asm volatile("" ::: "memory");
        if (nl) { issueX(i+1); issueB(d1, (s+3)&3); }
        mfma_phase(0, s & 3);
        // ---- phase 1 (power 2, tile s+1)
        if (nl) vmwait<P12>(); else vmwait<2>();
        __builtin_amdgcn_s_barrier();
        asm volatile("" ::: "memory");
        if (nl) issueB(d1 + SD, (s+4)&3);
        mfma_phase(1, (s+1) & 3);
        // ---- phase 2 (power 3, tile s+2)
        if (nl) vmwait<P12>(); else vmwait<0>();
        __builtin_amdgcn_s_barrier();
        asm volatile("" ::: "memory");
        if (nl) issueB(d1 + 2*SD, (s+5)&3);
        mfma_phase(2, (s+2) & 3);
        // ---- rebuild As for next iteration
        if (nl) {
            __builtin_amdgcn_s_barrier();       // all waves done reading As
            asm volatile("" ::: "memory");
            powers();                           // auto-wait xw (vmcnt(6))
            asm volatile("s_waitcnt lgkmcnt(0)" ::: "memory");
        }
    }

    // epilogue — C/D map: col = lane&15, row = (lane>>4)*4 + reg  [m89-verified]
    float bn[4];
    #pragma unroll
    for (int n = 0; n < 4; ++n) bn[n] = bias[n0 + wcol*64 + n*16 + ln15];

    #pragma unroll
    for (int m = 0; m < 4; ++m) {
        #pragma unroll
        for (int j = 0; j < 4; ++j) {
            const int gm = m0 + wrow*64 + m*16 + l4*4 + j;
            #pragma unroll
            for (int n = 0; n < 4; ++n) {
                const int gn = n0 + wcol*64 + n*16 + ln15;
                float v = 0.1f * (acc[m][n][j] + bn[n]);
                v = clip5(v);
                if (EPI == 1) {
                    float g = 0.5f * v * (1.f + erff(v * 0.70710678118654752f));
                    g = clip5(g);
                    gout[(size_t)gm * HH + gn] = (__bf16)g;
                } else {
                    yout[(size_t)gm * DD + gn] = v + resid[(size_t)gm * DD + gn];
                }
            }
        }
    }
}

// ---- row LayerNorm over D=1024, in-place, one block per row
__global__ __launch_bounds__(256) void ln_k(float* y,
                                            const float* __restrict__ gamma,
                                            const float* __restrict__ beta) {
    const int t = blockIdx.x, tid = threadIdx.x;
    const float4 v = reinterpret_cast<const float4*>(y + (size_t)t * DD)[tid];
    float s  = v.x + v.y + v.z + v.w;
    float s2 = v.x*v.x + v.y*v.y + v.z*v.z + v.w*v.w;
    #pragma unroll
    for (int off = 32; off > 0; off >>= 1) {
        s  += __shfl_down(s,  off, 64);
        s2 += __shfl_down(s2, off, 64);
    }
    __shared__ float rs[4], rs2[4];
    const int wave = tid >> 6, lane = tid & 63;
    if (lane == 0) { rs[wave] = s; rs2[wave] = s2; }
    __syncthreads();
    s  = rs[0] + rs[1] + rs[2] + rs[3];
    s2 = rs2[0] + rs2[1] + rs2[2] + rs2[3];
    const float mu  = s * (1.f / DD);
    const float var = s2 * (1.f / DD) - mu * mu;
    const float inv = rsqrtf(var + 1e-5f);
    const float4 g = reinterpret_cast<const float4*>(gamma)[tid];
    const float4 b = reinterpret_cast<const float4*>(beta)[tid];
    float4 o;
    o.x = (v.x - mu) * inv * g.x + b.x;
    o.y = (v.y - mu) * inv * g.y + b.y;
    o.z = (v.z - mu) * inv * g.z + b.z;
    o.w = (v.w - mu) * inv * g.w + b.w;
    reinterpret_cast<float4*>(y + (size_t)t * DD)[tid] = o;
}

extern "C" void kernel_launch(void* const* d_in, const int* in_sizes, int n_in,
                              void* d_out, int out_size, void* d_ws, size_t ws_size,
                              hipStream_t stream) {
    const float* x     = (const float*)d_in[0];
    const float* c1    = (const float*)d_in[1];
    const float* c2    = (const float*)d_in[2];
    const float* gamma = (const float*)d_in[3];
    const float* beta  = (const float*)d_in[4];
    float* out = (float*)d_out;

    // compact workspace: peak ~88 MiB
    char* ws = (char*)d_ws;
    const size_t OFF_G     = 0;            // g bf16 [TT][HH] = 67,108,864
    const size_t OFF_B     = 67108864;     // B1p/B2p shared (sequential liveness)
    const size_t OFF_BIAS1 = 92274688;     // HH*4
    const size_t OFF_BIAS2 = 92291072;     // DD*4

    __bf16* gbuf  = (__bf16*)(ws + OFF_G);
    ushort* B1p   = (ushort*)(ws + OFF_B);
    ushort* B2p   = (ushort*)(ws + OFF_B);
    float*  bias1 = (float*) (ws + OFF_BIAS1);
    float*  bias2 = (float*) (ws + OFF_BIAS2);

    pack_b<DD><<<HH, 256, 0, stream>>>(c1, B1p, bias1);
    gemm_k<1><<<dim3(HH / 128, TT / 128), 256, 0, stream>>>(
        (const void*)x, (const __bf16*)B1p, bias1, gbuf, nullptr, nullptr);
    pack_b<HH><<<DD, 256, 0, stream>>>(c2, B2p, bias2);      // reuses B region after GEMM1
    gemm_k<2><<<dim3(DD / 128, TT / 128), 256, 0, stream>>>(
        (const void*)gbuf, (const __bf16*)B2p, bias2, nullptr, x, (float*)out);
    ln_k<<<TT, 256, 0, stream>>>(out, gamma, beta);
}

// Round 5
// 492.131 us; speedup vs baseline: 1.6269x; 1.1013x over previous
//
#include <hip/hip_runtime.h>
#include <hip/hip_bf16.h>
#include <math.h>

// Problem dims (fixed by the reference)
#define DD 1024
#define HH 4096
#define TT 8192

typedef __attribute__((ext_vector_type(4))) float f32x4;
typedef __attribute__((ext_vector_type(8))) __bf16 bf16x8;
typedef __attribute__((ext_vector_type(4))) __bf16 bf16x4;

__device__ __forceinline__ ushort f2bf(float f) {
    union { float f; unsigned u; } v; v.f = f;
    unsigned r = v.u + 0x7FFFu + ((v.u >> 16) & 1u);   // RNE
    return (ushort)(r >> 16);
}
__device__ __forceinline__ float clip1(float v){ return fminf(fmaxf(v, -1.f), 1.f); }
__device__ __forceinline__ float clip5(float v){ return fminf(fmaxf(v, -5.f), 5.f); }

__device__ __forceinline__ void gload_lds16(const void* g, void* l) {
    __builtin_amdgcn_global_load_lds((const __attribute__((address_space(1))) void*)g,
                                     (__attribute__((address_space(3))) void*)l, 16, 0, 0);
}

template<int N> __device__ __forceinline__ void vmwait() {
    if      constexpr (N == 0) asm volatile("s_waitcnt vmcnt(0)" ::: "memory");
    else if constexpr (N == 2) asm volatile("s_waitcnt vmcnt(2)" ::: "memory");
    else if constexpr (N == 3) asm volatile("s_waitcnt vmcnt(3)" ::: "memory");
    else if constexpr (N == 4) asm volatile("s_waitcnt vmcnt(4)" ::: "memory");
}

// ---- pack coeff [N,4,DIN] fp32 -> B^T bf16 [N][3*DIN] (clip); k=0 slice -> bias[N]
template<int DIN>
__global__ __launch_bounds__(256) void pack_b(const float* __restrict__ c,
                                              ushort* __restrict__ Bp,
                                              float* __restrict__ bias) {
    const int n = blockIdx.x;
    const float* src = c + (size_t)n * 4 * DIN;
    ushort* dst = Bp + (size_t)n * 3 * DIN;
    float bsum = 0.f;
    for (int d = threadIdx.x; d < DIN; d += 256) {
        bsum += clip1(src[d]);
        dst[d]         = f2bf(clip1(src[DIN + d]));
        dst[DIN + d]   = f2bf(clip1(src[2*DIN + d]));
        dst[2*DIN + d] = f2bf(clip1(src[3*DIN + d]));
    }
    #pragma unroll
    for (int off = 32; off > 0; off >>= 1) bsum += __shfl_down(bsum, off, 64);
    __shared__ float red[4];
    const int wave = threadIdx.x >> 6, lane = threadIdx.x & 63;
    if (lane == 0) red[wave] = bsum;
    __syncthreads();
    if (threadIdx.x == 0) bias[n] = red[0] + red[1] + red[2] + red[3];
}

// ---- 128x256 bf16 MFMA GEMM, 8 waves, counted-vmcnt pipeline.
// B: 3-slot LDS ring (slot == power-phase), tile DMA'd 2 phases ahead,
//    pre-swizzled global source. A: src tile prefetched to regs (issue-early),
//    powers ds_written (write-late), 3 power planes, XOR-swizzled.
// EPI=1: src x fp32; C -> *0.1+bias, clip5, gelu, clip5 -> g bf16 [T][H]
// EPI=2: src g bf16; C -> *0.1+bias, clip5, +resid -> y fp32 [T][D]
template<int EPI>
__global__ __launch_bounds__(512, 4) void gemm_k(
    const void* __restrict__ Asrc, const __bf16* __restrict__ Bt,
    const float* __restrict__ bias,
    __bf16* __restrict__ gout,
    const float* __restrict__ resid, float* __restrict__ yout)
{
    constexpr int SD  = (EPI == 1) ? DD : HH;   // source width (one power group)
    constexpr int K   = 3 * SD;
    constexpr int NIT = SD / 32;
    constexpr int P1  = (EPI == 1) ? 4 : 3;     // steady-state vmcnt at phase 1

    __shared__ char LB[73728];                  // Bs ring 3*16384 @0; As 3*8192 @49152
    char* BsB = LB;
    char* AsB = LB + 49152;

    const int tid  = threadIdx.x;
    const int lane = tid & 63;
    const int wave = tid >> 6;
    const int wrow = wave >> 2, wcol = wave & 3;     // 2x4 waves of 64x64
    const int m0 = blockIdx.y * 128, n0 = blockIdx.x * 256;
    const int ln15 = lane & 15, l4 = lane >> 4;

    // swizzled frag-read byte offsets (T2: byte ^= ((row>>1)&3)<<4)
    int aoff[4], boff[4];
    #pragma unroll
    for (int m = 0; m < 4; ++m) {
        const int r = wrow*64 + m*16 + ln15;
        aoff[m] = r*64 + ((l4 ^ ((r>>1)&3)) << 4);
    }
    #pragma unroll
    for (int n = 0; n < 4; ++n) {
        const int r = wcol*64 + n*16 + ln15;
        boff[n] = r*64 + ((l4 ^ ((r>>1)&3)) << 4);
    }

    f32x4 acc[4][4];
    #pragma unroll
    for (int m = 0; m < 4; ++m)
        #pragma unroll
        for (int n = 0; n < 4; ++n)
            acc[m][n] = (f32x4){0.f, 0.f, 0.f, 0.f};

    // B tile DMA: [256][32] bf16; LDS dest linear, global source pre-swizzled
    auto issueB = [&](int kcol, int slot) {
        char* dst = BsB + (size_t)slot * 16384;
        #pragma unroll
        for (int it = 0; it < 2; ++it) {
            const int c = it*512 + tid, row = c >> 2, ch = c & 3, fr = (row>>1)&3;
            gload_lds16(Bt + (size_t)(n0 + row) * K + kcol + ((ch ^ fr) * 8),
                        dst + (size_t)c * 16);
        }
    };

    // A-source prefetch registers
    f32x4  xw[2];   // EPI==1: 2 chunks of 4 floats
    bf16x8 gw;      // EPI==2: 1 chunk of 8 bf16

    auto issueX = [&](int i) {
        if constexpr (EPI == 1) {
            const float* X = (const float*)Asrc;
            #pragma unroll
            for (int k = 0; k < 2; ++k) {
                const int c = k*512 + tid, row = c >> 3, ch = c & 7;
                xw[k] = *reinterpret_cast<const f32x4*>(
                    X + (size_t)(m0 + row) * DD + 32*i + ch*4);
            }
        } else {
            const __bf16* G = (const __bf16*)Asrc;
            const int row = tid >> 2, ch = tid & 3;
            gw = *reinterpret_cast<const bf16x8*>(
                G + (size_t)(m0 + row) * HH + 32*i + ch*8);
        }
    };

    auto powers = [&]() {
        if constexpr (EPI == 1) {
            #pragma unroll
            for (int k = 0; k < 2; ++k) {
                const int c = k*512 + tid, row = c >> 3, ch = c & 7, fr = (row>>1)&3;
                bf16x4 u0, u1, u2;
                #pragma unroll
                for (int j = 0; j < 4; ++j) {
                    const float v  = clip5(xw[k][j]);
                    const float v2 = v * v;
                    u0[j] = (__bf16)v; u1[j] = (__bf16)v2; u2[j] = (__bf16)(v2 * v);
                }
                const int base = row*64 + ((ch*8) ^ (fr << 4));
                *reinterpret_cast<bf16x4*>(AsB +         base) = u0;
                *reinterpret_cast<bf16x4*>(AsB +  8192 + base) = u1;
                *reinterpret_cast<bf16x4*>(AsB + 16384 + base) = u2;
            }
        } else {
            const int row = tid >> 2, ch = tid & 3, fr = (row>>1)&3;
            bf16x8 u1, u2;
            #pragma unroll
            for (int j = 0; j < 8; ++j) {
                const float v  = (float)gw[j];
                const float v2 = v * v;
                u1[j] = (__bf16)v2; u2[j] = (__bf16)(v2 * v);
            }
            const int base = row*64 + ((ch << 4) ^ (fr << 4));
            *reinterpret_cast<bf16x8*>(AsB +         base) = gw;
            *reinterpret_cast<bf16x8*>(AsB +  8192 + base) = u1;
            *reinterpret_cast<bf16x8*>(AsB + 16384 + base) = u2;
        }
    };

    auto mfma_phase = [&](int p) {               // As plane p, Bs slot p
        const char* As_ = AsB + p * 8192;
        const char* Bs_ = BsB + p * 16384;
        bf16x8 af[4], bf[4];
        #pragma unroll
        for (int m = 0; m < 4; ++m) af[m] = *reinterpret_cast<const bf16x8*>(As_ + aoff[m]);
        #pragma unroll
        for (int n = 0; n < 4; ++n) bf[n] = *reinterpret_cast<const bf16x8*>(Bs_ + boff[n]);
        __builtin_amdgcn_s_setprio(1);
        #pragma unroll
        for (int m = 0; m < 4; ++m)
            #pragma unroll
            for (int n = 0; n < 4; ++n)
                acc[m][n] = __builtin_amdgcn_mfma_f32_16x16x32_bf16(af[m], bf[n], acc[m][n], 0, 0, 0);
        __builtin_amdgcn_s_setprio(0);
    };

    // ---- prologue: x_0 regs; B tiles (p0,i0)->slot0, (p1,i0)->slot1; powers -> As
    issueX(0);
    issueB(0, 0);
    issueB(SD, 1);
    powers();                                   // compiler auto-waits xw (vmcnt(4))
    asm volatile("s_waitcnt lgkmcnt(0)" ::: "memory");

    for (int i = 0; i < NIT; ++i) {
        const bool nl = (i + 1 < NIT);
        const int d0 = 32*i, d1 = d0 + 32;
        // ---- phase 0 (power 1, slot 0)
        vmwait<2>();
        __builtin_amdgcn_s_barrier();
        asm volatile("" ::: "memory");
        if (nl) issueX(i+1);
        issueB(2*SD + d0, 2);                   // this iter's phase-2 tile
        mfma_phase(0);
        // ---- phase 1 (power 2, slot 1)
        if (nl) vmwait<P1>(); else vmwait<2>();
        __builtin_amdgcn_s_barrier();
        asm volatile("" ::: "memory");
        if (nl) issueB(d1, 0);                  // next iter phase-0 tile
        mfma_phase(1);
        // ---- phase 2 (power 3, slot 2)
        if (nl) vmwait<2>(); else vmwait<0>();
        __builtin_amdgcn_s_barrier();
        asm volatile("" ::: "memory");
        if (nl) issueB(SD + d1, 1);             // next iter phase-1 tile
        mfma_phase(2);
        // ---- rebuild As for next iteration
        if (nl) {
            __builtin_amdgcn_s_barrier();       // all waves done reading As
            asm volatile("" ::: "memory");
            powers();                           // auto-wait xw
            asm volatile("s_waitcnt lgkmcnt(0)" ::: "memory");
        }
    }

    // epilogue — C/D map: col = lane&15, row = (lane>>4)*4 + reg  [m89-verified]
    float bn[4];
    #pragma unroll
    for (int n = 0; n < 4; ++n) bn[n] = bias[n0 + wcol*64 + n*16 + ln15];

    #pragma unroll
    for (int m = 0; m < 4; ++m) {
        #pragma unroll
        for (int j = 0; j < 4; ++j) {
            const int gm = m0 + wrow*64 + m*16 + l4*4 + j;
            #pragma unroll
            for (int n = 0; n < 4; ++n) {
                const int gn = n0 + wcol*64 + n*16 + ln15;
                float v = 0.1f * (acc[m][n][j] + bn[n]);
                v = clip5(v);
                if (EPI == 1) {
                    float g = 0.5f * v * (1.f + erff(v * 0.70710678118654752f));
                    g = clip5(g);
                    gout[(size_t)gm * HH + gn] = (__bf16)g;
                } else {
                    yout[(size_t)gm * DD + gn] = v + resid[(size_t)gm * DD + gn];
                }
            }
        }
    }
}

// ---- row LayerNorm over D=1024, in-place, one block per row
__global__ __launch_bounds__(256) void ln_k(float* y,
                                            const float* __restrict__ gamma,
                                            const float* __restrict__ beta) {
    const int t = blockIdx.x, tid = threadIdx.x;
    const float4 v = reinterpret_cast<const float4*>(y + (size_t)t * DD)[tid];
    float s  = v.x + v.y + v.z + v.w;
    float s2 = v.x*v.x + v.y*v.y + v.z*v.z + v.w*v.w;
    #pragma unroll
    for (int off = 32; off > 0; off >>= 1) {
        s  += __shfl_down(s,  off, 64);
        s2 += __shfl_down(s2, off, 64);
    }
    __shared__ float rs[4], rs2[4];
    const int wave = tid >> 6, lane = tid & 63;
    if (lane == 0) { rs[wave] = s; rs2[wave] = s2; }
    __syncthreads();
    s  = rs[0] + rs[1] + rs[2] + rs[3];
    s2 = rs2[0] + rs2[1] + rs2[2] + rs2[3];
    const float mu  = s * (1.f / DD);
    const float var = s2 * (1.f / DD) - mu * mu;
    const float inv = rsqrtf(var + 1e-5f);
    const float4 g = reinterpret_cast<const float4*>(gamma)[tid];
    const float4 b = reinterpret_cast<const float4*>(beta)[tid];
    float4 o;
    o.x = (v.x - mu) * inv * g.x + b.x;
    o.y = (v.y - mu) * inv * g.y + b.y;
    o.z = (v.z - mu) * inv * g.z + b.z;
    o.w = (v.w - mu) * inv * g.w + b.w;
    reinterpret_cast<float4*>(y + (size_t)t * DD)[tid] = o;
}

extern "C" void kernel_launch(void* const* d_in, const int* in_sizes, int n_in,
                              void* d_out, int out_size, void* d_ws, size_t ws_size,
                              hipStream_t stream) {
    const float* x     = (const float*)d_in[0];
    const float* c1    = (const float*)d_in[1];
    const float* c2    = (const float*)d_in[2];
    const float* gamma = (const float*)d_in[3];
    const float* beta  = (const float*)d_in[4];
    float* out = (float*)d_out;

    // compact workspace: peak ~88 MiB
    char* ws = (char*)d_ws;
    const size_t OFF_G     = 0;            // g bf16 [TT][HH] = 67,108,864
    const size_t OFF_B     = 67108864;     // B1p/B2p shared (sequential liveness)
    const size_t OFF_BIAS1 = 92274688;     // HH*4
    const size_t OFF_BIAS2 = 92291072;     // DD*4

    __bf16* gbuf  = (__bf16*)(ws + OFF_G);
    ushort* B1p   = (ushort*)(ws + OFF_B);
    ushort* B2p   = (ushort*)(ws + OFF_B);
    float*  bias1 = (float*) (ws + OFF_BIAS1);
    float*  bias2 = (float*) (ws + OFF_BIAS2);

    pack_b<DD><<<HH, 256, 0, stream>>>(c1, B1p, bias1);
    gemm_k<1><<<dim3(HH / 256, TT / 128), 512, 0, stream>>>(
        (const void*)x, (const __bf16*)B1p, bias1, gbuf, nullptr, nullptr);
    pack_b<HH><<<DD, 256, 0, stream>>>(c2, B2p, bias2);      // reuses B region after GEMM1
    gemm_k<2><<<dim3(DD / 256, TT / 128), 512, 0, stream>>>(
        (const void*)gbuf, (const __bf16*)B2p, bias2, nullptr, x, (float*)out);
    ln_k<<<TT, 256, 0, stream>>>(out, gamma, beta);
}

// Round 6
// 478.318 us; speedup vs baseline: 1.6738x; 1.0289x over previous
//
#include <hip/hip_runtime.h>
#include <hip/hip_bf16.h>
#include <math.h>

// Problem dims (fixed by the reference)
#define DD 1024
#define HH 4096
#define TT 8192

typedef __attribute__((ext_vector_type(4))) float f32x4;
typedef __attribute__((ext_vector_type(8))) __bf16 bf16x8;
typedef __attribute__((ext_vector_type(4))) __bf16 bf16x4;

__device__ __forceinline__ ushort f2bf(float f) {
    union { float f; unsigned u; } v; v.f = f;
    unsigned r = v.u + 0x7FFFu + ((v.u >> 16) & 1u);   // RNE
    return (ushort)(r >> 16);
}
__device__ __forceinline__ float clip1(float v){ return fminf(fmaxf(v, -1.f), 1.f); }
__device__ __forceinline__ float clip5(float v){ return fminf(fmaxf(v, -5.f), 5.f); }

__device__ __forceinline__ void gload_lds16(const void* g, void* l) {
    __builtin_amdgcn_global_load_lds((const __attribute__((address_space(1))) void*)g,
                                     (__attribute__((address_space(3))) void*)l, 16, 0, 0);
}

template<int N> __device__ __forceinline__ void vmwait() {
    if      constexpr (N == 0) asm volatile("s_waitcnt vmcnt(0)" ::: "memory");
    else if constexpr (N == 1) asm volatile("s_waitcnt vmcnt(1)" ::: "memory");
    else if constexpr (N == 2) asm volatile("s_waitcnt vmcnt(2)" ::: "memory");
    else if constexpr (N == 3) asm volatile("s_waitcnt vmcnt(3)" ::: "memory");
    else if constexpr (N == 4) asm volatile("s_waitcnt vmcnt(4)" ::: "memory");
    else if constexpr (N == 6) asm volatile("s_waitcnt vmcnt(6)" ::: "memory");
}

// ---- pack coeff [N,4,DIN] fp32 -> B^T bf16 [N][3*DIN] (clip); k=0 slice -> bias[N]
template<int DIN>
__global__ __launch_bounds__(256) void pack_b(const float* __restrict__ c,
                                              ushort* __restrict__ Bp,
                                              float* __restrict__ bias) {
    const int n = blockIdx.x;
    const float* src = c + (size_t)n * 4 * DIN;
    ushort* dst = Bp + (size_t)n * 3 * DIN;
    float bsum = 0.f;
    for (int d = threadIdx.x; d < DIN; d += 256) {
        bsum += clip1(src[d]);
        dst[d]         = f2bf(clip1(src[DIN + d]));
        dst[DIN + d]   = f2bf(clip1(src[2*DIN + d]));
        dst[2*DIN + d] = f2bf(clip1(src[3*DIN + d]));
    }
    #pragma unroll
    for (int off = 32; off > 0; off >>= 1) bsum += __shfl_down(bsum, off, 64);
    __shared__ float red[4];
    const int wave = threadIdx.x >> 6, lane = threadIdx.x & 63;
    if (lane == 0) red[wave] = bsum;
    __syncthreads();
    if (threadIdx.x == 0) bias[n] = red[0] + red[1] + red[2] + red[3];
}

// ---- 256-row bf16 MFMA GEMM, 8 waves, counted-vmcnt pipeline, As double-buffer.
// B: 3-slot LDS ring (slot == power-phase), pre-swizzled global source.
// A: src tile -> regs at ph0 (issue-early); powers -> idle As buffer at end of
//    ph2 (write-late, overlapped with MFMA); 3 power planes, XOR-swizzled.
// EPI=1: 256x256, src x fp32;  C -> *0.1+bias, clip5, gelu, clip5 -> g bf16 [T][H]
// EPI=2: 256x128, src g bf16;  C -> *0.1+bias, clip5, +resid -> y fp32 [T][D]
template<int EPI>
__global__ __launch_bounds__(512, 2) void gemm_k(
    const void* __restrict__ Asrc, const __bf16* __restrict__ Bt,
    const float* __restrict__ bias,
    __bf16* __restrict__ gout,
    const float* __restrict__ resid, float* __restrict__ yout)
{
    constexpr int SD    = (EPI == 1) ? DD : HH;   // source width (one power group)
    constexpr int K     = 3 * SD;
    constexpr int NIT   = SD / 32;
    constexpr int BN    = (EPI == 1) ? 256 : 128;
    constexpr int MF    = (EPI == 1) ? 8 : 4;     // m-frags per wave
    constexpr int WN    = (EPI == 1) ? 4 : 2;     // waves along N
    constexpr int BCH   = (EPI == 1) ? 2 : 1;     // B-DMA chunks per thread
    constexpr int BSLOT = BN * 64;                // bytes per B slot ([BN][32] bf16)
    constexpr int APL   = 16384;                  // bytes per A plane ([256][32] bf16)
    constexpr int ABUF  = 3 * APL;
    constexpr int VB    = (EPI == 1) ? 2 : 1;     // steady vmcnt, phases 0/2
    constexpr int VP1   = (EPI == 1) ? 6 : 3;     // steady vmcnt, phase 1

    __shared__ char LB[2*ABUF + 3*BSLOT];         // EPI1: 144KB, EPI2: 120KB
    char* AsB = LB;
    char* BsB = LB + 2*ABUF;

    const int tid  = threadIdx.x;
    const int lane = tid & 63;
    const int wave = tid >> 6;
    const int wrow = wave / WN, wcol = wave % WN;
    const int m0 = blockIdx.y * 256, n0 = blockIdx.x * BN;
    const int ln15 = lane & 15, l4 = lane >> 4;

    // swizzled frag-read byte offsets (T2: byte ^= ((row>>1)&3)<<4)
    int aoff[MF], boff[4];
    #pragma unroll
    for (int m = 0; m < MF; ++m) {
        const int r = wrow*(MF*16) + m*16 + ln15;
        aoff[m] = r*64 + ((l4 ^ ((r>>1)&3)) << 4);
    }
    #pragma unroll
    for (int n = 0; n < 4; ++n) {
        const int r = wcol*64 + n*16 + ln15;
        boff[n] = r*64 + ((l4 ^ ((r>>1)&3)) << 4);
    }

    f32x4 acc[MF][4];
    #pragma unroll
    for (int m = 0; m < MF; ++m)
        #pragma unroll
        for (int n = 0; n < 4; ++n)
            acc[m][n] = (f32x4){0.f, 0.f, 0.f, 0.f};

    // B tile DMA: [BN][32] bf16; LDS dest linear, global source pre-swizzled
    auto issueB = [&](int kcol, int slot) {
        char* dst = BsB + slot * BSLOT;
        #pragma unroll
        for (int it = 0; it < BCH; ++it) {
            const int c = it*512 + tid, row = c >> 2, ch = c & 3, fr = (row>>1)&3;
            gload_lds16(Bt + (size_t)(n0 + row) * K + kcol + ((ch ^ fr) * 8),
                        dst + (size_t)c * 16);
        }
    };

    // A-source prefetch registers ([256][32] source tile, 16 elems/thread)
    f32x4  xw[4];   // EPI==1
    bf16x8 gw[2];   // EPI==2

    auto issueX = [&](int i) {
        if constexpr (EPI == 1) {
            const float* X = (const float*)Asrc;
            #pragma unroll
            for (int k = 0; k < 4; ++k) {
                const int c = k*512 + tid, row = c >> 3, ch = c & 7;
                xw[k] = *reinterpret_cast<const f32x4*>(
                    X + (size_t)(m0 + row) * DD + 32*i + ch*4);
            }
        } else {
            const __bf16* G = (const __bf16*)Asrc;
            #pragma unroll
            for (int k = 0; k < 2; ++k) {
                const int c = k*512 + tid, row = c >> 2, ch = c & 3;
                gw[k] = *reinterpret_cast<const bf16x8*>(
                    G + (size_t)(m0 + row) * HH + 32*i + ch*8);
            }
        }
    };

    auto powers = [&](char* Abuf) {
        if constexpr (EPI == 1) {
            #pragma unroll
            for (int k = 0; k < 4; ++k) {
                const int c = k*512 + tid, row = c >> 3, ch = c & 7, fr = (row>>1)&3;
                bf16x4 u0, u1, u2;
                #pragma unroll
                for (int j = 0; j < 4; ++j) {
                    const float v  = clip5(xw[k][j]);
                    const float v2 = v * v;
                    u0[j] = (__bf16)v; u1[j] = (__bf16)v2; u2[j] = (__bf16)(v2 * v);
                }
                const int base = row*64 + ((ch*8) ^ (fr << 4));
                *reinterpret_cast<bf16x4*>(Abuf +         base) = u0;
                *reinterpret_cast<bf16x4*>(Abuf +   APL + base) = u1;
                *reinterpret_cast<bf16x4*>(Abuf + 2*APL + base) = u2;
            }
        } else {
            #pragma unroll
            for (int k = 0; k < 2; ++k) {
                const int c = k*512 + tid, row = c >> 2, ch = c & 3, fr = (row>>1)&3;
                bf16x8 u1, u2;
                #pragma unroll
                for (int j = 0; j < 8; ++j) {
                    const float v  = (float)gw[k][j];
                    const float v2 = v * v;
                    u1[j] = (__bf16)v2; u2[j] = (__bf16)(v2 * v);
                }
                const int base = row*64 + ((ch << 4) ^ (fr << 4));
                *reinterpret_cast<bf16x8*>(Abuf +         base) = gw[k];
                *reinterpret_cast<bf16x8*>(Abuf +   APL + base) = u1;
                *reinterpret_cast<bf16x8*>(Abuf + 2*APL + base) = u2;
            }
        }
    };

    auto mfma_phase = [&](const char* Abuf, int p, int s) {
        const char* As_ = Abuf + p * APL;
        const char* Bs_ = BsB + s * BSLOT;
        bf16x8 af[MF], bf[4];
        #pragma unroll
        for (int m = 0; m < MF; ++m) af[m] = *reinterpret_cast<const bf16x8*>(As_ + aoff[m]);
        #pragma unroll
        for (int n = 0; n < 4; ++n) bf[n] = *reinterpret_cast<const bf16x8*>(Bs_ + boff[n]);
        __builtin_amdgcn_s_setprio(1);
        #pragma unroll
        for (int m = 0; m < MF; ++m)
            #pragma unroll
            for (int n = 0; n < 4; ++n)
                acc[m][n] = __builtin_amdgcn_mfma_f32_16x16x32_bf16(af[m], bf[n], acc[m][n], 0, 0, 0);
        __builtin_amdgcn_s_setprio(0);
    };

    // ---- prologue: src_0 regs; B(p0,0)->s0, B(p1,0)->s1; powers -> As buf0
    issueX(0);
    issueB(0, 0);
    issueB(SD, 1);
    powers(AsB);                                  // compiler auto-waits xw/gw
    asm volatile("s_waitcnt lgkmcnt(0)" ::: "memory");

    for (int i = 0; i < NIT; ++i) {
        const bool nl = (i + 1 < NIT);
        char* cur = AsB + (i & 1) * ABUF;
        char* nxt = AsB + ((i + 1) & 1) * ABUF;
        const int d0 = 32*i, d1 = d0 + 32;
        // ---- phase 0 (power 1, slot 0)
        vmwait<VB>();
        __builtin_amdgcn_s_barrier();
        asm volatile("" ::: "memory");
        if (nl) issueX(i+1);
        issueB(2*SD + d0, 2);                     // this iter's phase-2 tile
        mfma_phase(cur, 0, 0);
        // ---- phase 1 (power 2, slot 1)
        if (nl) vmwait<VP1>(); else vmwait<VB>();
        __builtin_amdgcn_s_barrier();
        asm volatile("" ::: "memory");
        if (nl) issueB(d1, 0);                    // next iter phase-0 tile
        mfma_phase(cur, 1, 1);
        // ---- phase 2 (power 3, slot 2)
        if (nl) vmwait<VB>(); else vmwait<0>();
        __builtin_amdgcn_s_barrier();
        asm volatile("" ::: "memory");
        if (nl) issueB(SD + d1, 1);               // next iter phase-1 tile
        mfma_phase(cur, 2, 2);
        if (nl) {
            powers(nxt);                          // write idle buffer, overlapped
            asm volatile("s_waitcnt lgkmcnt(0)" ::: "memory");
        }
    }

    // epilogue — C/D map: col = lane&15, row = (lane>>4)*4 + reg  [m89-verified]
    float bn[4];
    #pragma unroll
    for (int n = 0; n < 4; ++n) bn[n] = bias[n0 + wcol*64 + n*16 + ln15];

    #pragma unroll
    for (int m = 0; m < MF; ++m) {
        #pragma unroll
        for (int j = 0; j < 4; ++j) {
            const int gm = m0 + wrow*(MF*16) + m*16 + l4*4 + j;
            #pragma unroll
            for (int n = 0; n < 4; ++n) {
                const int gn = n0 + wcol*64 + n*16 + ln15;
                float v = 0.1f * (acc[m][n][j] + bn[n]);
                v = clip5(v);
                if (EPI == 1) {
                    float g = 0.5f * v * (1.f + erff(v * 0.70710678118654752f));
                    g = clip5(g);
                    gout[(size_t)gm * HH + gn] = (__bf16)g;
                } else {
                    yout[(size_t)gm * DD + gn] = v + resid[(size_t)gm * DD + gn];
                }
            }
        }
    }
}

// ---- row LayerNorm over D=1024, in-place, one block per row
__global__ __launch_bounds__(256) void ln_k(float* y,
                                            const float* __restrict__ gamma,
                                            const float* __restrict__ beta) {
    const int t = blockIdx.x, tid = threadIdx.x;
    const float4 v = reinterpret_cast<const float4*>(y + (size_t)t * DD)[tid];
    float s  = v.x + v.y + v.z + v.w;
    float s2 = v.x*v.x + v.y*v.y + v.z*v.z + v.w*v.w;
    #pragma unroll
    for (int off = 32; off > 0; off >>= 1) {
        s  += __shfl_down(s,  off, 64);
        s2 += __shfl_down(s2, off, 64);
    }
    __shared__ float rs[4], rs2[4];
    const int wave = tid >> 6, lane = tid & 63;
    if (lane == 0) { rs[wave] = s; rs2[wave] = s2; }
    __syncthreads();
    s  = rs[0] + rs[1] + rs[2] + rs[3];
    s2 = rs2[0] + rs2[1] + rs2[2] + rs2[3];
    const float mu  = s * (1.f / DD);
    const float var = s2 * (1.f / DD) - mu * mu;
    const float inv = rsqrtf(var + 1e-5f);
    const float4 g = reinterpret_cast<const float4*>(gamma)[tid];
    const float4 b = reinterpret_cast<const float4*>(beta)[tid];
    float4 o;
    o.x = (v.x - mu) * inv * g.x + b.x;
    o.y = (v.y - mu) * inv * g.y + b.y;
    o.z = (v.z - mu) * inv * g.z + b.z;
    o.w = (v.w - mu) * inv * g.w + b.w;
    reinterpret_cast<float4*>(y + (size_t)t * DD)[tid] = o;
}

extern "C" void kernel_launch(void* const* d_in, const int* in_sizes, int n_in,
                              void* d_out, int out_size, void* d_ws, size_t ws_size,
                              hipStream_t stream) {
    const float* x     = (const float*)d_in[0];
    const float* c1    = (const float*)d_in[1];
    const float* c2    = (const float*)d_in[2];
    const float* gamma = (const float*)d_in[3];
    const float* beta  = (const float*)d_in[4];
    float* out = (float*)d_out;

    // compact workspace: peak ~88 MiB
    char* ws = (char*)d_ws;
    const size_t OFF_G     = 0;            // g bf16 [TT][HH] = 67,108,864
    const size_t OFF_B     = 67108864;     // B1p/B2p shared (sequential liveness)
    const size_t OFF_BIAS1 = 92274688;     // HH*4
    const size_t OFF_BIAS2 = 92291072;     // DD*4

    __bf16* gbuf  = (__bf16*)(ws + OFF_G);
    ushort* B1p   = (ushort*)(ws + OFF_B);
    ushort* B2p   = (ushort*)(ws + OFF_B);
    float*  bias1 = (float*) (ws + OFF_BIAS1);
    float*  bias2 = (float*) (ws + OFF_BIAS2);

    pack_b<DD><<<HH, 256, 0, stream>>>(c1, B1p, bias1);
    gemm_k<1><<<dim3(HH / 256, TT / 256), 512, 0, stream>>>(
        (const void*)x, (const __bf16*)B1p, bias1, gbuf, nullptr, nullptr);
    pack_b<HH><<<DD, 256, 0, stream>>>(c2, B2p, bias2);      // reuses B region after GEMM1
    gemm_k<2><<<dim3(DD / 128, TT / 256), 512, 0, stream>>>(
        (const void*)gbuf, (const __bf16*)B2p, bias2, nullptr, x, (float*)out);
    ln_k<<<TT, 256, 0, stream>>>(out, gamma, beta);
}